// Round 10
// baseline (3795.813 us; speedup 1.0000x reference)
//
#include <hip/hip_runtime.h>
#include <math.h>

typedef float vf2 __attribute__((ext_vector_type(2)));

#define BATCH 4
#define IMG 64
#define NSAMP 24
#define HID 128
#define LATN 128
#define PIX 8
#define MPT (PIX*NSAMP)   /* 192 points per block */
#define FOV_T 0.57735026918962576f
#define CAMD 2.0f
#define NEARP 1.0f
#define STEP (2.0f/24.0f)
#define SHARP 50.0f

/* workspace layout (floats) */
#define WS_LAT1 0                    /* B*128 */
#define WS_CAMR (BATCH*HID)         /* B*12 at 512 */
#define WS_W2T  1024                 /* 128*128 */
#define WS_L1P  (1024 + HID*HID)     /* B*128 float4: (w1x,w1y,w1z,lat1) */

__global__ void setup_batch(const float* __restrict__ latents,
                            const float* __restrict__ phis,
                            const float* __restrict__ thetas,
                            const float* __restrict__ w1,
                            const float* __restrict__ b1,
                            float* __restrict__ ws) {
    int b = blockIdx.x, j = threadIdx.x;
    float acc = b1[j];
    for (int k = 0; k < LATN; ++k)
        acc = fmaf(latents[b*LATN + k], w1[(3+k)*HID + j], acc);
    ws[WS_LAT1 + b*HID + j] = acc;
    float4 pk = make_float4(w1[j], w1[HID + j], w1[2*HID + j], acc);
    *(float4*)&ws[WS_L1P + (b*HID + j)*4] = pk;
    if (j == 0) {
        float ph = phis[b], th = thetas[b];
        float cp = cosf(ph), sp = sinf(ph), ct = cosf(th), st = sinf(th);
        float cx = CAMD*cp*st, cy = CAMD*sp, cz = CAMD*cp*ct;
        float nc = sqrtf(cx*cx + cy*cy + cz*cz);
        float fx = -cx/nc, fy = -cy/nc, fz = -cz/nc;
        float rx = fz, rz = -fx;
        float nr = sqrtf(rx*rx + rz*rz);
        rx /= nr; rz /= nr;
        float ux = fy*rz;
        float uy = fz*rx - fx*rz;
        float uz = -fy*rx;
        float* c = ws + WS_CAMR + b*12;
        c[0]=cx; c[1]=cy; c[2]=cz;
        c[3]=rx; c[4]=0.0f; c[5]=rz;
        c[6]=ux; c[7]=uy; c[8]=uz;
        c[9]=fx; c[10]=fy; c[11]=fz;
    }
}

__global__ void setup_w2t(const float* __restrict__ w2, float* __restrict__ ws) {
    int j = blockIdx.x, k = threadIdx.x;
    ws[WS_W2T + j*HID + k] = w2[k*HID + j];
}

__global__ __launch_bounds__(256, 8)
void render_kernel(const float* __restrict__ samples_u,
                   const float* __restrict__ w1,
                   const float* __restrict__ w2,
                   const float* __restrict__ b2,
                   const float* __restrict__ w_sdf,
                   const float* __restrict__ b_sdf,
                   const float* __restrict__ w_tex,
                   const float* __restrict__ b_tex,
                   const float* __restrict__ ws,
                   float* __restrict__ out) {
    __shared__ __align__(16) float4 Ps4[MPT];   /* 3 KB */
    __shared__ float vals[MPT];
    __shared__ float vpart[4*MPT];              /* 3 KB */
    __shared__ float shadeH[4*HID];             /* 2 KB */
    __shared__ float shadeD[4*HID];             /* 2 KB */
    __shared__ float lat1s[HID];
    __shared__ float camR[12];
    __shared__ int   hitMs[PIX];
    __shared__ int   maskq[PIX];

    const int t    = threadIdx.x;
    const int lane = t & 63;
    const int wv   = __builtin_amdgcn_readfirstlane(t >> 6);  /* wave id 0..3 */
    const int blk  = blockIdx.x;
    const int b    = blk >> 9;
    const int tile = blk & 511;

    if (t < 12)  camR[t]  = ws[WS_CAMR + b*12 + t];
    if (t < HID) lat1s[t] = ws[WS_LAT1 + b*HID + t];
    if (t < PIX) {
        int p = tile*PIX + t;
        int x = p & 63, y = p >> 6;
        float xx = ((x + 0.5f)*(2.0f/IMG) - 1.0f)*FOV_T;
        float yy = ((y + 0.5f)*(2.0f/IMG) - 1.0f)*FOV_T;
        float n2 = xx*xx + yy*yy + 1.0f;
        maskq[t] = (4.0f - 3.0f*n2) >= 0.0f ? 1 : 0;
    }
    __syncthreads();

    /* fully-unmasked tile: write zeros, done */
    {
        int any = maskq[0]|maskq[1]|maskq[2]|maskq[3]|maskq[4]|maskq[5]|maskq[6]|maskq[7];
        if (!any) {
            if (t < PIX*3) {
                int q = t & 7, ch = t >> 3;
                int p = tile*PIX + q;
                int x = p & 63, y = p >> 6;
                out[((b*3 + ch)*IMG + y)*IMG + x] = 0.0f;
            }
            return;
        }
    }

    /* sample points for all 192 m */
    if (t < MPT) {
        int q = t / NSAMP, s = t - q*NSAMP;
        int p = tile*PIX + q;
        int x = p & 63, y = p >> 6;
        float xx =  ((x + 0.5f)*(2.0f/IMG) - 1.0f)*FOV_T;
        float yy = -(((y + 0.5f)*(2.0f/IMG) - 1.0f)*FOV_T);
        float inv = 1.0f/sqrtf(xx*xx + yy*yy + 1.0f);
        float d0 = xx*inv, d1 = yy*inv, d2 = -inv;
        float rxv = camR[3]*d0 + camR[6]*d1 - camR[9]*d2;
        float ryv = camR[4]*d0 + camR[7]*d1 - camR[10]*d2;
        float rzv = camR[5]*d0 + camR[8]*d1 - camR[11]*d2;
        float u  = samples_u[(y*IMG + x)*NSAMP + s];
        float tv = (s + u)*STEP + NEARP;
        Ps4[t] = make_float4(fmaf(rxv, tv, camR[0]),
                             fmaf(ryv, tv, camR[1]),
                             fmaf(rzv, tv, camR[2]), 0.0f);
    }
    __syncthreads();

    /* ---- march: fused single k-loop, 3 points/lane, scalar w2 path.
       Per-wave k-STAGGER: wave wv starts at row wv*32 (mod 128) so the
       4 waves (and 8 co-resident blocks) stream DIFFERENT w2 rows at any
       instant -> independent K$ miss streams, warm lines for trailers. ---- */
    {
        const float4* l1p = (const float4*)(ws + WS_L1P) + b*HID;   /* uniform */
        const vf2* b2v  = (const vf2*)b2    + wv*16;
        const vf2* wsdv = (const vf2*)w_sdf + wv*16;
        const float* wp = w2 + wv*32;        /* wave-uniform column slice */

        float4 P0 = Ps4[lane];
        float4 P1 = Ps4[64 + lane];
        float4 P2 = Ps4[128 + lane];

        vf2 a0[16], a1[16], a2[16];
        #pragma unroll
        for (int jj = 0; jj < 16; ++jj) { a0[jj] = 0.0f; a1[jj] = 0.0f; a2[jj] = 0.0f; }

        const int k0 = wv << 5;
        #pragma unroll 2
        for (int kk = 0; kk < HID; ++kk) {
            int k = (kk + k0) & (HID - 1);
            float4 wl = l1p[k];                                   /* s_load, K$ */
            const vf2* wr2 = (const vf2*)(wp + k*HID);            /* uniform slice */
            float z0 = fmaxf(fmaf(P0.x, wl.x, fmaf(P0.y, wl.y, fmaf(P0.z, wl.z, wl.w))), 0.0f);
            float z1 = fmaxf(fmaf(P1.x, wl.x, fmaf(P1.y, wl.y, fmaf(P1.z, wl.z, wl.w))), 0.0f);
            float z2 = fmaxf(fmaf(P2.x, wl.x, fmaf(P2.y, wl.y, fmaf(P2.z, wl.z, wl.w))), 0.0f);
            vf2 zz0 = z0, zz1 = z1, zz2 = z2;
            #pragma unroll
            for (int jj = 0; jj < 16; ++jj) {
                vf2 w = wr2[jj];
                a0[jj] = __builtin_elementwise_fma(zz0, w, a0[jj]);
                a1[jj] = __builtin_elementwise_fma(zz1, w, a1[jj]);
                a2[jj] = __builtin_elementwise_fma(zz2, w, a2[jj]);
            }
        }

        float v0 = 0.0f, v1 = 0.0f, v2 = 0.0f;
        #pragma unroll
        for (int jj = 0; jj < 16; ++jj) {
            vf2 bb = b2v[jj], wsd = wsdv[jj], zero = 0.0f;
            vf2 r0 = __builtin_elementwise_max(a0[jj] + bb, zero);
            vf2 r1 = __builtin_elementwise_max(a1[jj] + bb, zero);
            vf2 r2 = __builtin_elementwise_max(a2[jj] + bb, zero);
            v0 = fmaf(r0.x, wsd.x, fmaf(r0.y, wsd.y, v0));
            v1 = fmaf(r1.x, wsd.x, fmaf(r1.y, wsd.y, v1));
            v2 = fmaf(r2.x, wsd.x, fmaf(r2.y, wsd.y, v2));
        }
        vpart[wv*MPT +       lane] = v0;
        vpart[wv*MPT +  64 + lane] = v1;
        vpart[wv*MPT + 128 + lane] = v2;
    }
    __syncthreads();
    if (t < MPT)
        vals[t] = vpart[t] + vpart[MPT + t] + vpart[2*MPT + t]
                + vpart[3*MPT + t] + b_sdf[0];
    __syncthreads();

    /* hit selection */
    if (t < PIX) {
        int base = t*NSAMP;
        int idx = -1, bidx = 0;
        float bestv = 3.0e38f;
        for (int s = 0; s < NSAMP; ++s) {
            float v = vals[base + s];
            if (idx < 0 && v <= 0.0f) idx = s;
            if (v < bestv) { bestv = v; bidx = s; }
        }
        hitMs[t] = base + (idx >= 0 ? idx : bidx);
    }
    __syncthreads();

    /* ---- shading: one pixel per wave, 2 passes; wave-private LDS ---- */
    const float* w2t = ws + WS_W2T;
    const int j0 = lane, j1 = lane + 64;

    for (int pp = 0; pp < 2; ++pp) {
        int pt = pp*4 + wv;
        int hm = hitMs[pt];
        float4 H = Ps4[hm];
        float hx = H.x, hy = H.y, hz = H.z;

        float z0 = fmaf(hx, w1[j0], fmaf(hy, w1[HID+j0], fmaf(hz, w1[2*HID+j0], lat1s[j0])));
        float z1 = fmaf(hx, w1[j1], fmaf(hy, w1[HID+j1], fmaf(hz, w1[2*HID+j1], lat1s[j1])));
        float h10 = fmaxf(z0, 0.0f), h11 = fmaxf(z1, 0.0f);
        shadeH[wv*HID + j0] = h10;
        shadeH[wv*HID + j1] = h11;   /* intra-wave DS ordering suffices */

        /* forward h2 for j0,j1 with 4-way accumulators */
        float a00=0,a01=0,a02=0,a03=0, a10=0,a11=0,a12=0,a13=0;
        for (int k = 0; k < HID; k += 4) {
            float4 hv = *(const float4*)&shadeH[wv*HID + k];
            a00 = fmaf(hv.x, w2[(k+0)*HID + j0], a00);
            a10 = fmaf(hv.x, w2[(k+0)*HID + j1], a10);
            a01 = fmaf(hv.y, w2[(k+1)*HID + j0], a01);
            a11 = fmaf(hv.y, w2[(k+1)*HID + j1], a11);
            a02 = fmaf(hv.z, w2[(k+2)*HID + j0], a02);
            a12 = fmaf(hv.z, w2[(k+2)*HID + j1], a12);
            a03 = fmaf(hv.w, w2[(k+3)*HID + j0], a03);
            a13 = fmaf(hv.w, w2[(k+3)*HID + j1], a13);
        }
        float za = (a00+a01)+(a02+a03) + b2[j0];
        float zb = (a10+a11)+(a12+a13) + b2[j1];
        float h20 = fmaxf(za, 0.0f), h21 = fmaxf(zb, 0.0f);
        float wsd0 = w_sdf[j0], wsd1 = w_sdf[j1];
        shadeD[wv*HID + j0] = (za > 0.0f) ? wsd0 : 0.0f;
        shadeD[wv*HID + j1] = (zb > 0.0f) ? wsd1 : 0.0f;

        float pv = h20*wsd0 + h21*wsd1;
        float p0 = h20*w_tex[j0*3+0] + h21*w_tex[j1*3+0];
        float p1 = h20*w_tex[j0*3+1] + h21*w_tex[j1*3+1];
        float p2 = h20*w_tex[j0*3+2] + h21*w_tex[j1*3+2];
        #pragma unroll
        for (int off = 32; off > 0; off >>= 1) {
            pv += __shfl_xor(pv, off, 64);
            p0 += __shfl_xor(p0, off, 64);
            p1 += __shfl_xor(p1, off, 64);
            p2 += __shfl_xor(p2, off, 64);
        }

        /* backward: dh1 = w2t . dz2 */
        float d00=0,d01=0,d02=0,d03=0, d10=0,d11=0,d12=0,d13=0;
        for (int k = 0; k < HID; k += 4) {
            float4 dv = *(const float4*)&shadeD[wv*HID + k];
            d00 = fmaf(dv.x, w2t[(k+0)*HID + j0], d00);
            d10 = fmaf(dv.x, w2t[(k+0)*HID + j1], d10);
            d01 = fmaf(dv.y, w2t[(k+1)*HID + j0], d01);
            d11 = fmaf(dv.y, w2t[(k+1)*HID + j1], d11);
            d02 = fmaf(dv.z, w2t[(k+2)*HID + j0], d02);
            d12 = fmaf(dv.z, w2t[(k+2)*HID + j1], d12);
            d03 = fmaf(dv.w, w2t[(k+3)*HID + j0], d03);
            d13 = fmaf(dv.w, w2t[(k+3)*HID + j1], d13);
        }
        float dh0 = (d00+d01)+(d02+d03);
        float dh1v = (d10+d11)+(d12+d13);
        float dz10 = (h10 > 0.0f) ? dh0 : 0.0f;
        float dz11 = (h11 > 0.0f) ? dh1v : 0.0f;
        float g0 = w1[j0]*dz10 + w1[j1]*dz11;
        float g1 = w1[HID+j0]*dz10 + w1[HID+j1]*dz11;
        float g2 = w1[2*HID+j0]*dz10 + w1[2*HID+j1]*dz11;
        #pragma unroll
        for (int off = 32; off > 0; off >>= 1) {
            g0 += __shfl_xor(g0, off, 64);
            g1 += __shfl_xor(g1, off, 64);
            g2 += __shfl_xor(g2, off, 64);
        }

        if (lane == 0) {
            float val = pv + b_sdf[0];
            float nn = sqrtf(g0*g0 + g1*g1 + g2*g2) + 1e-8f;
            const float is3 = 0.57735026918962576f;
            float lam = (g0 + g1 + g2)*is3/nn;
            lam = fminf(fmaxf(lam, 0.0f), 1.0f);
            float hw = 1.0f/(1.0f + expf(val*SHARP));
            float sh = (0.2f + 0.8f*lam)*hw;
            int p = tile*PIX + pt;
            int x = p & 63, y = p >> 6;
            float o0 = 0.0f, o1 = 0.0f, o2 = 0.0f;
            if (maskq[pt]) {
                o0 = sh/(1.0f + expf(-(p0 + b_tex[0])));
                o1 = sh/(1.0f + expf(-(p1 + b_tex[1])));
                o2 = sh/(1.0f + expf(-(p2 + b_tex[2])));
            }
            out[((b*3 + 0)*IMG + y)*IMG + x] = o0;
            out[((b*3 + 1)*IMG + y)*IMG + x] = o1;
            out[((b*3 + 2)*IMG + y)*IMG + x] = o2;
        }
    }
}

extern "C" void kernel_launch(void* const* d_in, const int* in_sizes, int n_in,
                              void* d_out, int out_size, void* d_ws, size_t ws_size,
                              hipStream_t stream) {
    const float* latents   = (const float*)d_in[0];
    const float* phis      = (const float*)d_in[1];
    const float* thetas    = (const float*)d_in[2];
    const float* samples_u = (const float*)d_in[3];
    const float* w1        = (const float*)d_in[4];
    const float* b1        = (const float*)d_in[5];
    const float* w2        = (const float*)d_in[6];
    const float* b2        = (const float*)d_in[7];
    const float* w_sdf     = (const float*)d_in[8];
    const float* b_sdf     = (const float*)d_in[9];
    const float* w_tex     = (const float*)d_in[10];
    const float* b_tex     = (const float*)d_in[11];
    float* out = (float*)d_out;
    float* ws  = (float*)d_ws;

    setup_batch<<<dim3(BATCH), dim3(HID), 0, stream>>>(latents, phis, thetas, w1, b1, ws);
    setup_w2t<<<dim3(HID), dim3(HID), 0, stream>>>(w2, ws);
    render_kernel<<<dim3(BATCH*(IMG*IMG/PIX)), dim3(256), 0, stream>>>(
        samples_u, w1, w2, b2, w_sdf, b_sdf, w_tex, b_tex, ws, out);
}

// Round 11
// 401.028 us; speedup vs baseline: 9.4652x; 9.4652x over previous
//
#include <hip/hip_runtime.h>
#include <math.h>

typedef float vf2 __attribute__((ext_vector_type(2)));

#define BATCH 4
#define IMG 64
#define NSAMP 24
#define HID 128
#define LATN 128
#define PIX 8
#define MPT (PIX*NSAMP)   /* 192 points per block */
#define FOV_T 0.57735026918962576f
#define CAMD 2.0f
#define NEARP 1.0f
#define STEP (2.0f/24.0f)
#define SHARP 50.0f

/* workspace layout (floats) */
#define WS_LAT1 0                    /* B*128 */
#define WS_CAMR (BATCH*HID)         /* B*12 at 512 */
#define WS_W2T  1024                 /* 128*128 */
#define WS_L1P  (1024 + HID*HID)     /* B*128 float4: (w1x,w1y,w1z,lat1) */

__global__ void setup_batch(const float* __restrict__ latents,
                            const float* __restrict__ phis,
                            const float* __restrict__ thetas,
                            const float* __restrict__ w1,
                            const float* __restrict__ b1,
                            float* __restrict__ ws) {
    int b = blockIdx.x, j = threadIdx.x;
    float acc = b1[j];
    for (int k = 0; k < LATN; ++k)
        acc = fmaf(latents[b*LATN + k], w1[(3+k)*HID + j], acc);
    ws[WS_LAT1 + b*HID + j] = acc;
    float4 pk = make_float4(w1[j], w1[HID + j], w1[2*HID + j], acc);
    *(float4*)&ws[WS_L1P + (b*HID + j)*4] = pk;
    if (j == 0) {
        float ph = phis[b], th = thetas[b];
        float cp = cosf(ph), sp = sinf(ph), ct = cosf(th), st = sinf(th);
        float cx = CAMD*cp*st, cy = CAMD*sp, cz = CAMD*cp*ct;
        float nc = sqrtf(cx*cx + cy*cy + cz*cz);
        float fx = -cx/nc, fy = -cy/nc, fz = -cz/nc;
        float rx = fz, rz = -fx;
        float nr = sqrtf(rx*rx + rz*rz);
        rx /= nr; rz /= nr;
        float ux = fy*rz;
        float uy = fz*rx - fx*rz;
        float uz = -fy*rx;
        float* c = ws + WS_CAMR + b*12;
        c[0]=cx; c[1]=cy; c[2]=cz;
        c[3]=rx; c[4]=0.0f; c[5]=rz;
        c[6]=ux; c[7]=uy; c[8]=uz;
        c[9]=fx; c[10]=fy; c[11]=fz;
    }
}

__global__ void setup_w2t(const float* __restrict__ w2, float* __restrict__ ws) {
    int j = blockIdx.x, k = threadIdx.x;
    ws[WS_W2T + j*HID + k] = w2[k*HID + j];
}

__global__ __launch_bounds__(256, 4)
void render_kernel(const float* __restrict__ samples_u,
                   const float* __restrict__ w1,
                   const float* __restrict__ w2,
                   const float* __restrict__ b2,
                   const float* __restrict__ w_sdf,
                   const float* __restrict__ b_sdf,
                   const float* __restrict__ w_tex,
                   const float* __restrict__ b_tex,
                   const float* __restrict__ ws,
                   float* __restrict__ out) {
    __shared__ __align__(16) float4 Ps4[MPT];   /* 3 KB */
    __shared__ float vals[MPT];
    __shared__ float vpart[4*MPT];              /* 3 KB */
    __shared__ float shadeH[4*HID];             /* 2 KB */
    __shared__ float shadeD[4*HID];             /* 2 KB */
    __shared__ float lat1s[HID];
    __shared__ float camR[12];
    __shared__ int   hitMs[PIX];
    __shared__ int   maskq[PIX];

    const int t    = threadIdx.x;
    const int lane = t & 63;
    const int wv   = __builtin_amdgcn_readfirstlane(t >> 6);  /* wave id 0..3 */
    const int blk  = blockIdx.x;
    const int b    = blk >> 9;
    const int tile = blk & 511;

    if (t < 12)  camR[t]  = ws[WS_CAMR + b*12 + t];
    if (t < HID) lat1s[t] = ws[WS_LAT1 + b*HID + t];
    if (t < PIX) {
        int p = tile*PIX + t;
        int x = p & 63, y = p >> 6;
        float xx = ((x + 0.5f)*(2.0f/IMG) - 1.0f)*FOV_T;
        float yy = ((y + 0.5f)*(2.0f/IMG) - 1.0f)*FOV_T;
        float n2 = xx*xx + yy*yy + 1.0f;
        maskq[t] = (4.0f - 3.0f*n2) >= 0.0f ? 1 : 0;
    }
    __syncthreads();

    /* fully-unmasked tile: write zeros, done */
    {
        int any = maskq[0]|maskq[1]|maskq[2]|maskq[3]|maskq[4]|maskq[5]|maskq[6]|maskq[7];
        if (!any) {
            if (t < PIX*3) {
                int q = t & 7, ch = t >> 3;
                int p = tile*PIX + q;
                int x = p & 63, y = p >> 6;
                out[((b*3 + ch)*IMG + y)*IMG + x] = 0.0f;
            }
            return;
        }
    }

    /* sample points for all 192 m */
    if (t < MPT) {
        int q = t / NSAMP, s = t - q*NSAMP;
        int p = tile*PIX + q;
        int x = p & 63, y = p >> 6;
        float xx =  ((x + 0.5f)*(2.0f/IMG) - 1.0f)*FOV_T;
        float yy = -(((y + 0.5f)*(2.0f/IMG) - 1.0f)*FOV_T);
        float inv = 1.0f/sqrtf(xx*xx + yy*yy + 1.0f);
        float d0 = xx*inv, d1 = yy*inv, d2 = -inv;
        float rxv = camR[3]*d0 + camR[6]*d1 - camR[9]*d2;
        float ryv = camR[4]*d0 + camR[7]*d1 - camR[10]*d2;
        float rzv = camR[5]*d0 + camR[8]*d1 - camR[11]*d2;
        float u  = samples_u[(y*IMG + x)*NSAMP + s];
        float tv = (s + u)*STEP + NEARP;
        Ps4[t] = make_float4(fmaf(rxv, tv, camR[0]),
                             fmaf(ryv, tv, camR[1]),
                             fmaf(rzv, tv, camR[2]), 0.0f);
    }
    __syncthreads();

    /* ---- march: fused single k-loop, 3 points/lane, scalar w2 path.
       unroll 4: compute per 4-k group (~460 cyc) exceeds SMEM L2 latency
       (~300 cyc) so next group's s_loads hide under current compute. ---- */
    {
        const float4* l1p = (const float4*)(ws + WS_L1P) + b*HID;   /* uniform */
        const vf2* b2v  = (const vf2*)b2    + wv*16;
        const vf2* wsdv = (const vf2*)w_sdf + wv*16;
        const float* wp = w2 + wv*32;        /* wave-uniform column slice */

        float4 P0 = Ps4[lane];
        float4 P1 = Ps4[64 + lane];
        float4 P2 = Ps4[128 + lane];

        vf2 a0[16], a1[16], a2[16];
        #pragma unroll
        for (int jj = 0; jj < 16; ++jj) { a0[jj] = 0.0f; a1[jj] = 0.0f; a2[jj] = 0.0f; }

        #pragma unroll 4
        for (int k = 0; k < HID; ++k) {
            float4 wl = l1p[k];                                   /* s_load, K$ */
            const vf2* wr2 = (const vf2*)(wp + k*HID);            /* uniform slice */
            float z0 = fmaxf(fmaf(P0.x, wl.x, fmaf(P0.y, wl.y, fmaf(P0.z, wl.z, wl.w))), 0.0f);
            float z1 = fmaxf(fmaf(P1.x, wl.x, fmaf(P1.y, wl.y, fmaf(P1.z, wl.z, wl.w))), 0.0f);
            float z2 = fmaxf(fmaf(P2.x, wl.x, fmaf(P2.y, wl.y, fmaf(P2.z, wl.z, wl.w))), 0.0f);
            vf2 zz0 = z0, zz1 = z1, zz2 = z2;
            #pragma unroll
            for (int jj = 0; jj < 16; ++jj) {
                vf2 w = wr2[jj];
                a0[jj] = __builtin_elementwise_fma(zz0, w, a0[jj]);
                a1[jj] = __builtin_elementwise_fma(zz1, w, a1[jj]);
                a2[jj] = __builtin_elementwise_fma(zz2, w, a2[jj]);
            }
        }

        float v0 = 0.0f, v1 = 0.0f, v2 = 0.0f;
        #pragma unroll
        for (int jj = 0; jj < 16; ++jj) {
            vf2 bb = b2v[jj], wsd = wsdv[jj], zero = 0.0f;
            vf2 r0 = __builtin_elementwise_max(a0[jj] + bb, zero);
            vf2 r1 = __builtin_elementwise_max(a1[jj] + bb, zero);
            vf2 r2 = __builtin_elementwise_max(a2[jj] + bb, zero);
            v0 = fmaf(r0.x, wsd.x, fmaf(r0.y, wsd.y, v0));
            v1 = fmaf(r1.x, wsd.x, fmaf(r1.y, wsd.y, v1));
            v2 = fmaf(r2.x, wsd.x, fmaf(r2.y, wsd.y, v2));
        }
        vpart[wv*MPT +       lane] = v0;
        vpart[wv*MPT +  64 + lane] = v1;
        vpart[wv*MPT + 128 + lane] = v2;
    }
    __syncthreads();
    if (t < MPT)
        vals[t] = vpart[t] + vpart[MPT + t] + vpart[2*MPT + t]
                + vpart[3*MPT + t] + b_sdf[0];
    __syncthreads();

    /* hit selection */
    if (t < PIX) {
        int base = t*NSAMP;
        int idx = -1, bidx = 0;
        float bestv = 3.0e38f;
        for (int s = 0; s < NSAMP; ++s) {
            float v = vals[base + s];
            if (idx < 0 && v <= 0.0f) idx = s;
            if (v < bestv) { bestv = v; bidx = s; }
        }
        hitMs[t] = base + (idx >= 0 ? idx : bidx);
    }
    __syncthreads();

    /* ---- shading: one pixel per wave, 2 passes; wave-private LDS ---- */
    const float* w2t = ws + WS_W2T;
    const int j0 = lane, j1 = lane + 64;

    for (int pp = 0; pp < 2; ++pp) {
        int pt = pp*4 + wv;
        int hm = hitMs[pt];
        float4 H = Ps4[hm];
        float hx = H.x, hy = H.y, hz = H.z;

        float z0 = fmaf(hx, w1[j0], fmaf(hy, w1[HID+j0], fmaf(hz, w1[2*HID+j0], lat1s[j0])));
        float z1 = fmaf(hx, w1[j1], fmaf(hy, w1[HID+j1], fmaf(hz, w1[2*HID+j1], lat1s[j1])));
        float h10 = fmaxf(z0, 0.0f), h11 = fmaxf(z1, 0.0f);
        shadeH[wv*HID + j0] = h10;
        shadeH[wv*HID + j1] = h11;   /* intra-wave DS ordering suffices */

        /* forward h2 for j0,j1 with 4-way accumulators */
        float a00=0,a01=0,a02=0,a03=0, a10=0,a11=0,a12=0,a13=0;
        for (int k = 0; k < HID; k += 4) {
            float4 hv = *(const float4*)&shadeH[wv*HID + k];
            a00 = fmaf(hv.x, w2[(k+0)*HID + j0], a00);
            a10 = fmaf(hv.x, w2[(k+0)*HID + j1], a10);
            a01 = fmaf(hv.y, w2[(k+1)*HID + j0], a01);
            a11 = fmaf(hv.y, w2[(k+1)*HID + j1], a11);
            a02 = fmaf(hv.z, w2[(k+2)*HID + j0], a02);
            a12 = fmaf(hv.z, w2[(k+2)*HID + j1], a12);
            a03 = fmaf(hv.w, w2[(k+3)*HID + j0], a03);
            a13 = fmaf(hv.w, w2[(k+3)*HID + j1], a13);
        }
        float za = (a00+a01)+(a02+a03) + b2[j0];
        float zb = (a10+a11)+(a12+a13) + b2[j1];
        float h20 = fmaxf(za, 0.0f), h21 = fmaxf(zb, 0.0f);
        float wsd0 = w_sdf[j0], wsd1 = w_sdf[j1];
        shadeD[wv*HID + j0] = (za > 0.0f) ? wsd0 : 0.0f;
        shadeD[wv*HID + j1] = (zb > 0.0f) ? wsd1 : 0.0f;

        float pv = h20*wsd0 + h21*wsd1;
        float p0 = h20*w_tex[j0*3+0] + h21*w_tex[j1*3+0];
        float p1 = h20*w_tex[j0*3+1] + h21*w_tex[j1*3+1];
        float p2 = h20*w_tex[j0*3+2] + h21*w_tex[j1*3+2];
        #pragma unroll
        for (int off = 32; off > 0; off >>= 1) {
            pv += __shfl_xor(pv, off, 64);
            p0 += __shfl_xor(p0, off, 64);
            p1 += __shfl_xor(p1, off, 64);
            p2 += __shfl_xor(p2, off, 64);
        }

        /* backward: dh1 = w2t . dz2 */
        float d00=0,d01=0,d02=0,d03=0, d10=0,d11=0,d12=0,d13=0;
        for (int k = 0; k < HID; k += 4) {
            float4 dv = *(const float4*)&shadeD[wv*HID + k];
            d00 = fmaf(dv.x, w2t[(k+0)*HID + j0], d00);
            d10 = fmaf(dv.x, w2t[(k+0)*HID + j1], d10);
            d01 = fmaf(dv.y, w2t[(k+1)*HID + j0], d01);
            d11 = fmaf(dv.y, w2t[(k+1)*HID + j1], d11);
            d02 = fmaf(dv.z, w2t[(k+2)*HID + j0], d02);
            d12 = fmaf(dv.z, w2t[(k+2)*HID + j1], d12);
            d03 = fmaf(dv.w, w2t[(k+3)*HID + j0], d03);
            d13 = fmaf(dv.w, w2t[(k+3)*HID + j1], d13);
        }
        float dh0 = (d00+d01)+(d02+d03);
        float dh1v = (d10+d11)+(d12+d13);
        float dz10 = (h10 > 0.0f) ? dh0 : 0.0f;
        float dz11 = (h11 > 0.0f) ? dh1v : 0.0f;
        float g0 = w1[j0]*dz10 + w1[j1]*dz11;
        float g1 = w1[HID+j0]*dz10 + w1[HID+j1]*dz11;
        float g2 = w1[2*HID+j0]*dz10 + w1[2*HID+j1]*dz11;
        #pragma unroll
        for (int off = 32; off > 0; off >>= 1) {
            g0 += __shfl_xor(g0, off, 64);
            g1 += __shfl_xor(g1, off, 64);
            g2 += __shfl_xor(g2, off, 64);
        }

        if (lane == 0) {
            float val = pv + b_sdf[0];
            float nn = sqrtf(g0*g0 + g1*g1 + g2*g2) + 1e-8f;
            const float is3 = 0.57735026918962576f;
            float lam = (g0 + g1 + g2)*is3/nn;
            lam = fminf(fmaxf(lam, 0.0f), 1.0f);
            float hw = 1.0f/(1.0f + expf(val*SHARP));
            float sh = (0.2f + 0.8f*lam)*hw;
            int p = tile*PIX + pt;
            int x = p & 63, y = p >> 6;
            float o0 = 0.0f, o1 = 0.0f, o2 = 0.0f;
            if (maskq[pt]) {
                o0 = sh/(1.0f + expf(-(p0 + b_tex[0])));
                o1 = sh/(1.0f + expf(-(p1 + b_tex[1])));
                o2 = sh/(1.0f + expf(-(p2 + b_tex[2])));
            }
            out[((b*3 + 0)*IMG + y)*IMG + x] = o0;
            out[((b*3 + 1)*IMG + y)*IMG + x] = o1;
            out[((b*3 + 2)*IMG + y)*IMG + x] = o2;
        }
    }
}

extern "C" void kernel_launch(void* const* d_in, const int* in_sizes, int n_in,
                              void* d_out, int out_size, void* d_ws, size_t ws_size,
                              hipStream_t stream) {
    const float* latents   = (const float*)d_in[0];
    const float* phis      = (const float*)d_in[1];
    const float* thetas    = (const float*)d_in[2];
    const float* samples_u = (const float*)d_in[3];
    const float* w1        = (const float*)d_in[4];
    const float* b1        = (const float*)d_in[5];
    const float* w2        = (const float*)d_in[6];
    const float* b2        = (const float*)d_in[7];
    const float* w_sdf     = (const float*)d_in[8];
    const float* b_sdf     = (const float*)d_in[9];
    const float* w_tex     = (const float*)d_in[10];
    const float* b_tex     = (const float*)d_in[11];
    float* out = (float*)d_out;
    float* ws  = (float*)d_ws;

    setup_batch<<<dim3(BATCH), dim3(HID), 0, stream>>>(latents, phis, thetas, w1, b1, ws);
    setup_w2t<<<dim3(HID), dim3(HID), 0, stream>>>(w2, ws);
    render_kernel<<<dim3(BATCH*(IMG*IMG/PIX)), dim3(256), 0, stream>>>(
        samples_u, w1, w2, b2, w_sdf, b_sdf, w_tex, b_tex, ws, out);
}

// Round 12
// 218.694 us; speedup vs baseline: 17.3567x; 1.8337x over previous
//
#include <hip/hip_runtime.h>
#include <math.h>

typedef short bf16x8 __attribute__((ext_vector_type(8)));
typedef float f32x4 __attribute__((ext_vector_type(4)));

#define BATCH 4
#define IMG 64
#define NSAMP 24
#define HID 128
#define LATN 128
#define PIX 8
#define MPT (PIX*NSAMP)   /* 192 points per block = 12 M-tiles of 16 */
#define FOV_T 0.57735026918962576f
#define CAMD 2.0f
#define NEARP 1.0f
#define STEP (2.0f/24.0f)
#define SHARP 50.0f

/* workspace layout (float units) */
#define WS_LAT1 0                      /* B*128 */
#define WS_CAMR 512                    /* B*12 */
#define WS_W2T  1024                   /* 128*128 */
#define WS_L1P  17408                  /* B*128 float4 = 2048 floats */
#define WS_W2S  19456                  /* 3*4*8*64*8 ushorts = 24576 floats */

__device__ __forceinline__ unsigned short f2bf(float f) {
    unsigned int u = __float_as_uint(f);
    u = u + 0x7FFFu + ((u >> 16) & 1u);
    return (unsigned short)(u >> 16);
}
__device__ __forceinline__ float bf2f(unsigned short s) {
    return __uint_as_float(((unsigned int)s) << 16);
}

__global__ void setup_batch(const float* __restrict__ latents,
                            const float* __restrict__ phis,
                            const float* __restrict__ thetas,
                            const float* __restrict__ w1,
                            const float* __restrict__ b1,
                            float* __restrict__ ws) {
    int b = blockIdx.x, j = threadIdx.x;
    float acc = b1[j];
    for (int k = 0; k < LATN; ++k)
        acc = fmaf(latents[b*LATN + k], w1[(3+k)*HID + j], acc);
    ws[WS_LAT1 + b*HID + j] = acc;
    float4 pk = make_float4(w1[j], w1[HID + j], w1[2*HID + j], acc);
    *(float4*)&ws[WS_L1P + (b*HID + j)*4] = pk;
    if (j == 0) {
        float ph = phis[b], th = thetas[b];
        float cp = cosf(ph), sp = sinf(ph), ct = cosf(th), st = sinf(th);
        float cx = CAMD*cp*st, cy = CAMD*sp, cz = CAMD*cp*ct;
        float nc = sqrtf(cx*cx + cy*cy + cz*cz);
        float fx = -cx/nc, fy = -cy/nc, fz = -cz/nc;
        float rx = fz, rz = -fx;
        float nr = sqrtf(rx*rx + rz*rz);
        rx /= nr; rz /= nr;
        float ux = fy*rz;
        float uy = fz*rx - fx*rz;
        float uz = -fy*rx;
        float* c = ws + WS_CAMR + b*12;
        c[0]=cx; c[1]=cy; c[2]=cz;
        c[3]=rx; c[4]=0.0f; c[5]=rz;
        c[6]=ux; c[7]=uy; c[8]=uz;
        c[9]=fx; c[10]=fy; c[11]=fz;
    }
}

__global__ void setup_w2t(const float* __restrict__ w2, float* __restrict__ ws) {
    int j = blockIdx.x, k = threadIdx.x;
    ws[WS_W2T + j*HID + k] = w2[k*HID + j];
}

/* split w2 into 3 bf16 matrices, stored in MFMA B-fragment order:
   w2s[s][k0][n0][lane][i] with n = n0*16 + (lane&15), k = k0*32 + (lane>>4)*8 + i */
__global__ void setup_w2s(const float* __restrict__ w2, unsigned short* __restrict__ w2s) {
    int id = blockIdx.x*256 + threadIdx.x;   /* 0..2047 */
    int k0 = id >> 9, n0 = (id >> 6) & 7, l = id & 63;
    int n = n0*16 + (l & 15);
    #pragma unroll
    for (int i = 0; i < 8; ++i) {
        int k = k0*32 + (l >> 4)*8 + i;
        float w = w2[k*HID + n];
        unsigned short u0 = f2bf(w);   float f0 = bf2f(u0);
        float r1 = w - f0;  unsigned short u1 = f2bf(r1); float f1 = bf2f(u1);
        float r2 = r1 - f1; unsigned short u2 = f2bf(r2);
        int base = ((k0*8 + n0)*64 + l)*8 + i;
        w2s[base]         = u0;
        w2s[16384 + base] = u1;
        w2s[32768 + base] = u2;
    }
}

__global__ __launch_bounds__(256, 2)
void render_kernel(const float* __restrict__ samples_u,
                   const float* __restrict__ w1,
                   const float* __restrict__ w2,
                   const float* __restrict__ b2,
                   const float* __restrict__ w_sdf,
                   const float* __restrict__ b_sdf,
                   const float* __restrict__ w_tex,
                   const float* __restrict__ b_tex,
                   const float* __restrict__ ws,
                   float* __restrict__ out) {
    __shared__ __align__(16) float4 Ps4[MPT];   /* 3 KB */
    __shared__ __align__(16) float4 l1ps[HID];  /* 2 KB */
    __shared__ float vals[MPT];
    __shared__ float b2s[HID];
    __shared__ float wsds[HID];
    __shared__ float shadeH[4*HID];             /* 2 KB */
    __shared__ float shadeD[4*HID];             /* 2 KB */
    __shared__ float lat1s[HID];
    __shared__ float camR[12];
    __shared__ int   hitMs[PIX];
    __shared__ int   maskq[PIX];

    const int t    = threadIdx.x;
    const int lane = t & 63;
    const int wv   = __builtin_amdgcn_readfirstlane(t >> 6);  /* wave id 0..3 */
    const int blk  = blockIdx.x;
    const int b    = blk >> 9;
    const int tile = blk & 511;

    if (t < 12)  camR[t]  = ws[WS_CAMR + b*12 + t];
    if (t < HID) {
        lat1s[t] = ws[WS_LAT1 + b*HID + t];
        l1ps[t]  = ((const float4*)(ws + WS_L1P))[b*HID + t];
        b2s[t]   = b2[t];
        wsds[t]  = w_sdf[t];
    }
    if (t < PIX) {
        int p = tile*PIX + t;
        int x = p & 63, y = p >> 6;
        float xx = ((x + 0.5f)*(2.0f/IMG) - 1.0f)*FOV_T;
        float yy = ((y + 0.5f)*(2.0f/IMG) - 1.0f)*FOV_T;
        float n2 = xx*xx + yy*yy + 1.0f;
        maskq[t] = (4.0f - 3.0f*n2) >= 0.0f ? 1 : 0;
    }
    __syncthreads();

    /* fully-unmasked tile: write zeros, done */
    {
        int any = maskq[0]|maskq[1]|maskq[2]|maskq[3]|maskq[4]|maskq[5]|maskq[6]|maskq[7];
        if (!any) {
            if (t < PIX*3) {
                int q = t & 7, ch = t >> 3;
                int p = tile*PIX + q;
                int x = p & 63, y = p >> 6;
                out[((b*3 + ch)*IMG + y)*IMG + x] = 0.0f;
            }
            return;
        }
    }

    /* sample points for all 192 m */
    if (t < MPT) {
        int q = t / NSAMP, s = t - q*NSAMP;
        int p = tile*PIX + q;
        int x = p & 63, y = p >> 6;
        float xx =  ((x + 0.5f)*(2.0f/IMG) - 1.0f)*FOV_T;
        float yy = -(((y + 0.5f)*(2.0f/IMG) - 1.0f)*FOV_T);
        float inv = 1.0f/sqrtf(xx*xx + yy*yy + 1.0f);
        float d0 = xx*inv, d1 = yy*inv, d2 = -inv;
        float rxv = camR[3]*d0 + camR[6]*d1 - camR[9]*d2;
        float ryv = camR[4]*d0 + camR[7]*d1 - camR[10]*d2;
        float rzv = camR[5]*d0 + camR[8]*d1 - camR[11]*d2;
        float u  = samples_u[(y*IMG + x)*NSAMP + s];
        float tv = (s + u)*STEP + NEARP;
        Ps4[t] = make_float4(fmaf(rxv, tv, camR[0]),
                             fmaf(ryv, tv, camR[1]),
                             fmaf(rzv, tv, camR[2]), 0.0f);
    }
    __syncthreads();

    /* ---- march via bf16 triple-split MFMA (6 products, err ~2^-24):
       wave owns 3 M-tiles x 8 N-tiles. A (h1 splits) built on the fly from
       l1ps; B (w2 splits) preloaded in fragment order from workspace.
       bf16 error affects hit INDEX only; shading recomputes val in fp32. ---- */
    {
        const unsigned short* w2s = (const unsigned short*)(ws + WS_W2S);
        const int lm = lane & 15, lg = lane >> 4;
        const float bsdf = b_sdf[0];

        float4 Pm0 = Ps4[(wv*3+0)*16 + lm];
        float4 Pm1 = Ps4[(wv*3+1)*16 + lm];
        float4 Pm2 = Ps4[(wv*3+2)*16 + lm];

        f32x4 acc[3][8];
        #pragma unroll
        for (int mt = 0; mt < 3; ++mt)
            #pragma unroll
            for (int n0 = 0; n0 < 8; ++n0)
                acc[mt][n0] = (f32x4)(0.0f);

        for (int k0 = 0; k0 < 4; ++k0) {
            bf16x8 a0[3], a1[3], a2[3];
            #pragma unroll
            for (int mt = 0; mt < 3; ++mt) {
                float4 P = (mt == 0) ? Pm0 : ((mt == 1) ? Pm1 : Pm2);
                #pragma unroll
                for (int i = 0; i < 8; ++i) {
                    float4 wl = l1ps[k0*32 + lg*8 + i];
                    float h = fmaxf(fmaf(P.x, wl.x, fmaf(P.y, wl.y, fmaf(P.z, wl.z, wl.w))), 0.0f);
                    unsigned short u0 = f2bf(h);  float f0 = bf2f(u0);
                    float r1 = h - f0;  unsigned short u1 = f2bf(r1); float f1 = bf2f(u1);
                    float r2 = r1 - f1; unsigned short u2 = f2bf(r2);
                    a0[mt][i] = (short)u0; a1[mt][i] = (short)u1; a2[mt][i] = (short)u2;
                }
            }
            const unsigned short* wk = w2s + (k0*8)*512 + lane*8;
            #pragma unroll
            for (int n0 = 0; n0 < 8; ++n0) {
                bf16x8 B0 = *(const bf16x8*)(wk + n0*512);
                bf16x8 B1 = *(const bf16x8*)(wk + 16384 + n0*512);
                bf16x8 B2 = *(const bf16x8*)(wk + 32768 + n0*512);
                #pragma unroll
                for (int mt = 0; mt < 3; ++mt) {
                    f32x4 c = acc[mt][n0];
                    c = __builtin_amdgcn_mfma_f32_16x16x32_bf16(a0[mt], B0, c, 0, 0, 0);
                    c = __builtin_amdgcn_mfma_f32_16x16x32_bf16(a0[mt], B1, c, 0, 0, 0);
                    c = __builtin_amdgcn_mfma_f32_16x16x32_bf16(a1[mt], B0, c, 0, 0, 0);
                    c = __builtin_amdgcn_mfma_f32_16x16x32_bf16(a0[mt], B2, c, 0, 0, 0);
                    c = __builtin_amdgcn_mfma_f32_16x16x32_bf16(a1[mt], B1, c, 0, 0, 0);
                    c = __builtin_amdgcn_mfma_f32_16x16x32_bf16(a2[mt], B0, c, 0, 0, 0);
                    acc[mt][n0] = c;
                }
            }
        }

        /* epilogue: vals[m] = sum_j relu(z2+b2)*wsdf + bsdf
           D layout: col j = n0*16 + lm, row = lg*4 + r (guide §3, m89) */
        #pragma unroll
        for (int mt = 0; mt < 3; ++mt) {
            float ps0 = 0.0f, ps1 = 0.0f, ps2 = 0.0f, ps3 = 0.0f;
            #pragma unroll
            for (int n0 = 0; n0 < 8; ++n0) {
                int j = n0*16 + lm;
                float bb = b2s[j], wd = wsds[j];
                ps0 += fmaxf(acc[mt][n0][0] + bb, 0.0f)*wd;
                ps1 += fmaxf(acc[mt][n0][1] + bb, 0.0f)*wd;
                ps2 += fmaxf(acc[mt][n0][2] + bb, 0.0f)*wd;
                ps3 += fmaxf(acc[mt][n0][3] + bb, 0.0f)*wd;
            }
            #pragma unroll
            for (int off = 1; off < 16; off <<= 1) {
                ps0 += __shfl_xor(ps0, off, 64);
                ps1 += __shfl_xor(ps1, off, 64);
                ps2 += __shfl_xor(ps2, off, 64);
                ps3 += __shfl_xor(ps3, off, 64);
            }
            if (lm == 0) {
                int mg = (wv*3 + mt)*16 + lg*4;
                vals[mg+0] = ps0 + bsdf;
                vals[mg+1] = ps1 + bsdf;
                vals[mg+2] = ps2 + bsdf;
                vals[mg+3] = ps3 + bsdf;
            }
        }
    }
    __syncthreads();

    /* hit selection */
    if (t < PIX) {
        int base = t*NSAMP;
        int idx = -1, bidx = 0;
        float bestv = 3.0e38f;
        for (int s = 0; s < NSAMP; ++s) {
            float v = vals[base + s];
            if (idx < 0 && v <= 0.0f) idx = s;
            if (v < bestv) { bestv = v; bidx = s; }
        }
        hitMs[t] = base + (idx >= 0 ? idx : bidx);
    }
    __syncthreads();

    /* ---- shading: one pixel per wave, 2 passes; all fp32 (exact) ---- */
    const float* w2t = ws + WS_W2T;
    const int j0 = lane, j1 = lane + 64;

    for (int pp = 0; pp < 2; ++pp) {
        int pt = pp*4 + wv;
        int hm = hitMs[pt];
        float4 H = Ps4[hm];
        float hx = H.x, hy = H.y, hz = H.z;

        float z0 = fmaf(hx, w1[j0], fmaf(hy, w1[HID+j0], fmaf(hz, w1[2*HID+j0], lat1s[j0])));
        float z1 = fmaf(hx, w1[j1], fmaf(hy, w1[HID+j1], fmaf(hz, w1[2*HID+j1], lat1s[j1])));
        float h10 = fmaxf(z0, 0.0f), h11 = fmaxf(z1, 0.0f);
        shadeH[wv*HID + j0] = h10;
        shadeH[wv*HID + j1] = h11;   /* intra-wave DS ordering suffices */

        float a00=0,a01=0,a02=0,a03=0, a10=0,a11=0,a12=0,a13=0;
        for (int k = 0; k < HID; k += 4) {
            float4 hv = *(const float4*)&shadeH[wv*HID + k];
            a00 = fmaf(hv.x, w2[(k+0)*HID + j0], a00);
            a10 = fmaf(hv.x, w2[(k+0)*HID + j1], a10);
            a01 = fmaf(hv.y, w2[(k+1)*HID + j0], a01);
            a11 = fmaf(hv.y, w2[(k+1)*HID + j1], a11);
            a02 = fmaf(hv.z, w2[(k+2)*HID + j0], a02);
            a12 = fmaf(hv.z, w2[(k+2)*HID + j1], a12);
            a03 = fmaf(hv.w, w2[(k+3)*HID + j0], a03);
            a13 = fmaf(hv.w, w2[(k+3)*HID + j1], a13);
        }
        float za = (a00+a01)+(a02+a03) + b2[j0];
        float zb = (a10+a11)+(a12+a13) + b2[j1];
        float h20 = fmaxf(za, 0.0f), h21 = fmaxf(zb, 0.0f);
        float wsd0 = w_sdf[j0], wsd1 = w_sdf[j1];
        shadeD[wv*HID + j0] = (za > 0.0f) ? wsd0 : 0.0f;
        shadeD[wv*HID + j1] = (zb > 0.0f) ? wsd1 : 0.0f;

        float pv = h20*wsd0 + h21*wsd1;
        float p0 = h20*w_tex[j0*3+0] + h21*w_tex[j1*3+0];
        float p1 = h20*w_tex[j0*3+1] + h21*w_tex[j1*3+1];
        float p2 = h20*w_tex[j0*3+2] + h21*w_tex[j1*3+2];
        #pragma unroll
        for (int off = 32; off > 0; off >>= 1) {
            pv += __shfl_xor(pv, off, 64);
            p0 += __shfl_xor(p0, off, 64);
            p1 += __shfl_xor(p1, off, 64);
            p2 += __shfl_xor(p2, off, 64);
        }

        float d00=0,d01=0,d02=0,d03=0, d10=0,d11=0,d12=0,d13=0;
        for (int k = 0; k < HID; k += 4) {
            float4 dv = *(const float4*)&shadeD[wv*HID + k];
            d00 = fmaf(dv.x, w2t[(k+0)*HID + j0], d00);
            d10 = fmaf(dv.x, w2t[(k+0)*HID + j1], d10);
            d01 = fmaf(dv.y, w2t[(k+1)*HID + j0], d01);
            d11 = fmaf(dv.y, w2t[(k+1)*HID + j1], d11);
            d02 = fmaf(dv.z, w2t[(k+2)*HID + j0], d02);
            d12 = fmaf(dv.z, w2t[(k+2)*HID + j1], d12);
            d03 = fmaf(dv.w, w2t[(k+3)*HID + j0], d03);
            d13 = fmaf(dv.w, w2t[(k+3)*HID + j1], d13);
        }
        float dh0 = (d00+d01)+(d02+d03);
        float dh1v = (d10+d11)+(d12+d13);
        float dz10 = (h10 > 0.0f) ? dh0 : 0.0f;
        float dz11 = (h11 > 0.0f) ? dh1v : 0.0f;
        float g0 = w1[j0]*dz10 + w1[j1]*dz11;
        float g1 = w1[HID+j0]*dz10 + w1[HID+j1]*dz11;
        float g2 = w1[2*HID+j0]*dz10 + w1[2*HID+j1]*dz11;
        #pragma unroll
        for (int off = 32; off > 0; off >>= 1) {
            g0 += __shfl_xor(g0, off, 64);
            g1 += __shfl_xor(g1, off, 64);
            g2 += __shfl_xor(g2, off, 64);
        }

        if (lane == 0) {
            float val = pv + b_sdf[0];
            float nn = sqrtf(g0*g0 + g1*g1 + g2*g2) + 1e-8f;
            const float is3 = 0.57735026918962576f;
            float lam = (g0 + g1 + g2)*is3/nn;
            lam = fminf(fmaxf(lam, 0.0f), 1.0f);
            float hw = 1.0f/(1.0f + expf(val*SHARP));
            float sh = (0.2f + 0.8f*lam)*hw;
            int p = tile*PIX + pt;
            int x = p & 63, y = p >> 6;
            float o0 = 0.0f, o1 = 0.0f, o2 = 0.0f;
            if (maskq[pt]) {
                o0 = sh/(1.0f + expf(-(p0 + b_tex[0])));
                o1 = sh/(1.0f + expf(-(p1 + b_tex[1])));
                o2 = sh/(1.0f + expf(-(p2 + b_tex[2])));
            }
            out[((b*3 + 0)*IMG + y)*IMG + x] = o0;
            out[((b*3 + 1)*IMG + y)*IMG + x] = o1;
            out[((b*3 + 2)*IMG + y)*IMG + x] = o2;
        }
    }
}

extern "C" void kernel_launch(void* const* d_in, const int* in_sizes, int n_in,
                              void* d_out, int out_size, void* d_ws, size_t ws_size,
                              hipStream_t stream) {
    const float* latents   = (const float*)d_in[0];
    const float* phis      = (const float*)d_in[1];
    const float* thetas    = (const float*)d_in[2];
    const float* samples_u = (const float*)d_in[3];
    const float* w1        = (const float*)d_in[4];
    const float* b1        = (const float*)d_in[5];
    const float* w2        = (const float*)d_in[6];
    const float* b2        = (const float*)d_in[7];
    const float* w_sdf     = (const float*)d_in[8];
    const float* b_sdf     = (const float*)d_in[9];
    const float* w_tex     = (const float*)d_in[10];
    const float* b_tex     = (const float*)d_in[11];
    float* out = (float*)d_out;
    float* ws  = (float*)d_ws;

    setup_batch<<<dim3(BATCH), dim3(HID), 0, stream>>>(latents, phis, thetas, w1, b1, ws);
    setup_w2t<<<dim3(HID), dim3(HID), 0, stream>>>(w2, ws);
    setup_w2s<<<dim3(8), dim3(256), 0, stream>>>(w2, (unsigned short*)(ws + WS_W2S));
    render_kernel<<<dim3(BATCH*(IMG*IMG/PIX)), dim3(256), 0, stream>>>(
        samples_u, w1, w2, b2, w_sdf, b_sdf, w_tex, b_tex, ws, out);
}

// Round 13
// 192.985 us; speedup vs baseline: 19.6690x; 1.1332x over previous
//
#include <hip/hip_runtime.h>
#include <math.h>

typedef short bf16x8 __attribute__((ext_vector_type(8)));
typedef float f32x4 __attribute__((ext_vector_type(4)));

#define BATCH 4
#define IMG 64
#define NSAMP 24
#define HID 128
#define LATN 128
#define PIX 8
#define MPT (PIX*NSAMP)   /* 192 points per block = 12 M-tiles of 16 */
#define FOV_T 0.57735026918962576f
#define CAMD 2.0f
#define NEARP 1.0f
#define STEP (2.0f/24.0f)
#define SHARP 50.0f

/* workspace layout (float units) */
#define WS_LAT1 0                      /* B*128 */
#define WS_CAMR 512                    /* B*12 */
#define WS_W2T  1024                   /* 128*128 */
#define WS_L1P  17408                  /* B*128 float4 = 2048 floats */
#define WS_W2S  19456                  /* 3*16384 ushorts = 24576 floats */

__device__ __forceinline__ unsigned short f2bf(float f) {
    unsigned int u = __float_as_uint(f);
    u = u + 0x7FFFu + ((u >> 16) & 1u);
    return (unsigned short)(u >> 16);
}
__device__ __forceinline__ float bf2f(unsigned short s) {
    return __uint_as_float(((unsigned int)s) << 16);
}

/* fused setup: blocks 0-3 per-batch; 4-67 w2 transpose; 68-75 w2 bf16 splits */
__global__ void setup_all(const float* __restrict__ latents,
                          const float* __restrict__ phis,
                          const float* __restrict__ thetas,
                          const float* __restrict__ w1,
                          const float* __restrict__ b1,
                          const float* __restrict__ w2,
                          float* __restrict__ ws) {
    const int bid = blockIdx.x, t = threadIdx.x;
    if (bid < 4) {
        if (t < HID) {
            int b = bid, j = t;
            float acc = b1[j];
            for (int k = 0; k < LATN; ++k)
                acc = fmaf(latents[b*LATN + k], w1[(3+k)*HID + j], acc);
            ws[WS_LAT1 + b*HID + j] = acc;
            float4 pk = make_float4(w1[j], w1[HID + j], w1[2*HID + j], acc);
            *(float4*)&ws[WS_L1P + (b*HID + j)*4] = pk;
            if (j == 0) {
                float ph = phis[b], th = thetas[b];
                float cp = cosf(ph), sp = sinf(ph), ct = cosf(th), st = sinf(th);
                float cx = CAMD*cp*st, cy = CAMD*sp, cz = CAMD*cp*ct;
                float nc = sqrtf(cx*cx + cy*cy + cz*cz);
                float fx = -cx/nc, fy = -cy/nc, fz = -cz/nc;
                float rx = fz, rz = -fx;
                float nr = sqrtf(rx*rx + rz*rz);
                rx /= nr; rz /= nr;
                float ux = fy*rz;
                float uy = fz*rx - fx*rz;
                float uz = -fy*rx;
                float* c = ws + WS_CAMR + b*12;
                c[0]=cx; c[1]=cy; c[2]=cz;
                c[3]=rx; c[4]=0.0f; c[5]=rz;
                c[6]=ux; c[7]=uy; c[8]=uz;
                c[9]=fx; c[10]=fy; c[11]=fz;
            }
        }
    } else if (bid < 68) {
        int id = (bid - 4)*256 + t;          /* 0..16383 */
        int j = id >> 7, k = id & 127;
        ws[WS_W2T + j*HID + k] = w2[k*HID + j];
    } else {
        int id = (bid - 68)*256 + t;         /* 0..2047 */
        unsigned short* w2s = (unsigned short*)(ws + WS_W2S);
        int k0 = id >> 9, n0 = (id >> 6) & 7, l = id & 63;
        int n = n0*16 + (l & 15);
        #pragma unroll
        for (int i = 0; i < 8; ++i) {
            int k = k0*32 + (l >> 4)*8 + i;
            float w = w2[k*HID + n];
            unsigned short u0 = f2bf(w);   float f0 = bf2f(u0);
            float r1 = w - f0;  unsigned short u1 = f2bf(r1); float f1 = bf2f(u1);
            float r2 = r1 - f1; unsigned short u2 = f2bf(r2);
            int base = ((k0*8 + n0)*64 + l)*8 + i;
            w2s[base]         = u0;
            w2s[16384 + base] = u1;
            w2s[32768 + base] = u2;
        }
    }
}

__global__ __launch_bounds__(256, 2)
void render_kernel(const float* __restrict__ samples_u,
                   const float* __restrict__ w1,
                   const float* __restrict__ w2,
                   const float* __restrict__ b2,
                   const float* __restrict__ w_sdf,
                   const float* __restrict__ b_sdf,
                   const float* __restrict__ w_tex,
                   const float* __restrict__ b_tex,
                   const float* __restrict__ ws,
                   float* __restrict__ out) {
    __shared__ __align__(16) float4 Ps4[MPT];     /* 3 KB */
    __shared__ __align__(16) float4 l1ps[HID];    /* 2 KB */
    __shared__ __align__(16) float4 shadeHT[HID*2];  /* h1[k][p] as 2 float4 per k, 4 KB */
    __shared__ __align__(16) float4 dz2s[HID*2];     /* dz2[j][p], 4 KB */
    __shared__ float vals[MPT];
    __shared__ float b2s[HID];
    __shared__ float wsds[HID];
    __shared__ float lat1s[HID];
    __shared__ float camR[12];
    __shared__ float redp[4][16];
    __shared__ float redg[4][12];
    __shared__ int   hitMs[PIX];
    __shared__ int   maskq[PIX];

    const int t    = threadIdx.x;
    const int lane = t & 63;
    const int wv   = __builtin_amdgcn_readfirstlane(t >> 6);  /* wave id 0..3 */
    const int blk  = blockIdx.x;
    const int b    = blk >> 9;
    const int tile = blk & 511;

    if (t < 12)  camR[t]  = ws[WS_CAMR + b*12 + t];
    if (t < HID) {
        lat1s[t] = ws[WS_LAT1 + b*HID + t];
        l1ps[t]  = ((const float4*)(ws + WS_L1P))[b*HID + t];
        b2s[t]   = b2[t];
        wsds[t]  = w_sdf[t];
    }
    if (t < PIX) {
        int p = tile*PIX + t;
        int x = p & 63, y = p >> 6;
        float xx = ((x + 0.5f)*(2.0f/IMG) - 1.0f)*FOV_T;
        float yy = ((y + 0.5f)*(2.0f/IMG) - 1.0f)*FOV_T;
        float n2 = xx*xx + yy*yy + 1.0f;
        maskq[t] = (4.0f - 3.0f*n2) >= 0.0f ? 1 : 0;
    }
    __syncthreads();

    /* fully-unmasked tile: write zeros, done */
    {
        int any = maskq[0]|maskq[1]|maskq[2]|maskq[3]|maskq[4]|maskq[5]|maskq[6]|maskq[7];
        if (!any) {
            if (t < PIX*3) {
                int q = t & 7, ch = t >> 3;
                int p = tile*PIX + q;
                int x = p & 63, y = p >> 6;
                out[((b*3 + ch)*IMG + y)*IMG + x] = 0.0f;
            }
            return;
        }
    }

    /* sample points for all 192 m */
    if (t < MPT) {
        int q = t / NSAMP, s = t - q*NSAMP;
        int p = tile*PIX + q;
        int x = p & 63, y = p >> 6;
        float xx =  ((x + 0.5f)*(2.0f/IMG) - 1.0f)*FOV_T;
        float yy = -(((y + 0.5f)*(2.0f/IMG) - 1.0f)*FOV_T);
        float inv = 1.0f/sqrtf(xx*xx + yy*yy + 1.0f);
        float d0 = xx*inv, d1 = yy*inv, d2 = -inv;
        float rxv = camR[3]*d0 + camR[6]*d1 - camR[9]*d2;
        float ryv = camR[4]*d0 + camR[7]*d1 - camR[10]*d2;
        float rzv = camR[5]*d0 + camR[8]*d1 - camR[11]*d2;
        float u  = samples_u[(y*IMG + x)*NSAMP + s];
        float tv = (s + u)*STEP + NEARP;
        Ps4[t] = make_float4(fmaf(rxv, tv, camR[0]),
                             fmaf(ryv, tv, camR[1]),
                             fmaf(rzv, tv, camR[2]), 0.0f);
    }
    __syncthreads();

    /* ---- march via bf16 triple-split MFMA (6 products, err ~2^-24) ---- */
    {
        const unsigned short* w2s = (const unsigned short*)(ws + WS_W2S);
        const int lm = lane & 15, lg = lane >> 4;
        const float bsdf = b_sdf[0];

        float4 Pm0 = Ps4[(wv*3+0)*16 + lm];
        float4 Pm1 = Ps4[(wv*3+1)*16 + lm];
        float4 Pm2 = Ps4[(wv*3+2)*16 + lm];

        f32x4 acc[3][8];
        #pragma unroll
        for (int mt = 0; mt < 3; ++mt)
            #pragma unroll
            for (int n0 = 0; n0 < 8; ++n0)
                acc[mt][n0] = (f32x4)(0.0f);

        for (int k0 = 0; k0 < 4; ++k0) {
            bf16x8 a0[3], a1[3], a2[3];
            #pragma unroll
            for (int mt = 0; mt < 3; ++mt) {
                float4 P = (mt == 0) ? Pm0 : ((mt == 1) ? Pm1 : Pm2);
                #pragma unroll
                for (int i = 0; i < 8; ++i) {
                    float4 wl = l1ps[k0*32 + lg*8 + i];
                    float h = fmaxf(fmaf(P.x, wl.x, fmaf(P.y, wl.y, fmaf(P.z, wl.z, wl.w))), 0.0f);
                    unsigned short u0 = f2bf(h);  float f0 = bf2f(u0);
                    float r1 = h - f0;  unsigned short u1 = f2bf(r1); float f1 = bf2f(u1);
                    float r2 = r1 - f1; unsigned short u2 = f2bf(r2);
                    a0[mt][i] = (short)u0; a1[mt][i] = (short)u1; a2[mt][i] = (short)u2;
                }
            }
            const unsigned short* wk = w2s + (k0*8)*512 + lane*8;
            #pragma unroll
            for (int n0 = 0; n0 < 8; ++n0) {
                bf16x8 B0 = *(const bf16x8*)(wk + n0*512);
                bf16x8 B1 = *(const bf16x8*)(wk + 16384 + n0*512);
                bf16x8 B2 = *(const bf16x8*)(wk + 32768 + n0*512);
                #pragma unroll
                for (int mt = 0; mt < 3; ++mt) {
                    f32x4 c = acc[mt][n0];
                    c = __builtin_amdgcn_mfma_f32_16x16x32_bf16(a0[mt], B0, c, 0, 0, 0);
                    c = __builtin_amdgcn_mfma_f32_16x16x32_bf16(a0[mt], B1, c, 0, 0, 0);
                    c = __builtin_amdgcn_mfma_f32_16x16x32_bf16(a1[mt], B0, c, 0, 0, 0);
                    c = __builtin_amdgcn_mfma_f32_16x16x32_bf16(a0[mt], B2, c, 0, 0, 0);
                    c = __builtin_amdgcn_mfma_f32_16x16x32_bf16(a1[mt], B1, c, 0, 0, 0);
                    c = __builtin_amdgcn_mfma_f32_16x16x32_bf16(a2[mt], B0, c, 0, 0, 0);
                    acc[mt][n0] = c;
                }
            }
        }

        /* epilogue: vals[m]; D layout col=n0*16+lm, row=lg*4+r */
        #pragma unroll
        for (int mt = 0; mt < 3; ++mt) {
            float ps0 = 0.0f, ps1 = 0.0f, ps2 = 0.0f, ps3 = 0.0f;
            #pragma unroll
            for (int n0 = 0; n0 < 8; ++n0) {
                int j = n0*16 + lm;
                float bb = b2s[j], wd = wsds[j];
                ps0 += fmaxf(acc[mt][n0][0] + bb, 0.0f)*wd;
                ps1 += fmaxf(acc[mt][n0][1] + bb, 0.0f)*wd;
                ps2 += fmaxf(acc[mt][n0][2] + bb, 0.0f)*wd;
                ps3 += fmaxf(acc[mt][n0][3] + bb, 0.0f)*wd;
            }
            #pragma unroll
            for (int off = 1; off < 16; off <<= 1) {
                ps0 += __shfl_xor(ps0, off, 64);
                ps1 += __shfl_xor(ps1, off, 64);
                ps2 += __shfl_xor(ps2, off, 64);
                ps3 += __shfl_xor(ps3, off, 64);
            }
            if (lm == 0) {
                int mg = (wv*3 + mt)*16 + lg*4;
                vals[mg+0] = ps0 + b_sdf[0];
                vals[mg+1] = ps1 + b_sdf[0];
                vals[mg+2] = ps2 + b_sdf[0];
                vals[mg+3] = ps3 + b_sdf[0];
            }
        }
    }
    __syncthreads();

    /* hit selection */
    if (t < PIX) {
        int base = t*NSAMP;
        int idx = -1, bidx = 0;
        float bestv = 3.0e38f;
        for (int s = 0; s < NSAMP; ++s) {
            float v = vals[base + s];
            if (idx < 0 && v <= 0.0f) idx = s;
            if (v < bestv) { bestv = v; bidx = s; }
        }
        hitMs[t] = base + (idx >= 0 ? idx : bidx);
    }
    __syncthreads();

    /* ---- shading v2: stream w2/w2t ONCE for all 8 pixels (fp32 exact) ---- */

    /* step 1: h1 for 8 hit points, transposed [k][p] (float4 pairs) */
    #pragma unroll
    for (int i = 0; i < 4; ++i) {
        int idx = i*256 + t;
        int p = idx & 7, k = idx >> 3;
        float4 wl = l1ps[k];
        float4 P  = Ps4[hitMs[p]];
        float h = fmaxf(fmaf(P.x, wl.x, fmaf(P.y, wl.y, fmaf(P.z, wl.z, wl.w))), 0.0f);
        ((float*)shadeHT)[k*8 + p] = h;
    }
    __syncthreads();

    /* step 2: forward. thread = column j, half ph -> 4 pixels */
    {
        const int j = t & 127, ph = t >> 7;
        float ac0 = 0.0f, ac1 = 0.0f, ac2 = 0.0f, ac3 = 0.0f;
        const float* w2col = w2 + j;
        #pragma unroll 8
        for (int k = 0; k < HID; ++k) {
            float wv2 = w2col[k*HID];
            float4 hk = shadeHT[k*2 + ph];
            ac0 = fmaf(hk.x, wv2, ac0);
            ac1 = fmaf(hk.y, wv2, ac1);
            ac2 = fmaf(hk.z, wv2, ac2);
            ac3 = fmaf(hk.w, wv2, ac3);
        }
        float b2j = b2s[j], wsdj = wsds[j];
        float tx0 = w_tex[j*3+0], tx1 = w_tex[j*3+1], tx2 = w_tex[j*3+2];
        float z[4] = {ac0 + b2j, ac1 + b2j, ac2 + b2j, ac3 + b2j};
        float4 dzv;
        float vp[4], tp0[4], tp1[4], tp2[4];
        #pragma unroll
        for (int pp = 0; pp < 4; ++pp) {
            float h2 = fmaxf(z[pp], 0.0f);
            ((float*)&dzv)[pp] = (z[pp] > 0.0f) ? wsdj : 0.0f;
            vp[pp]  = h2*wsdj;
            tp0[pp] = h2*tx0;
            tp1[pp] = h2*tx1;
            tp2[pp] = h2*tx2;
        }
        dz2s[j*2 + ph] = dzv;
        #pragma unroll
        for (int pp = 0; pp < 4; ++pp) {
            float v = vp[pp], a = tp0[pp], bt = tp1[pp], c = tp2[pp];
            #pragma unroll
            for (int off = 32; off > 0; off >>= 1) {
                v  += __shfl_xor(v,  off, 64);
                a  += __shfl_xor(a,  off, 64);
                bt += __shfl_xor(bt, off, 64);
                c  += __shfl_xor(c,  off, 64);
            }
            if (lane == 0) {
                redp[wv][pp*4+0] = v;
                redp[wv][pp*4+1] = a;
                redp[wv][pp*4+2] = bt;
                redp[wv][pp*4+3] = c;
            }
        }
    }
    __syncthreads();

    /* step 3: backward. thread = row k, half ph -> 4 pixels */
    {
        const int k = t & 127, ph = t >> 7;
        float d0 = 0.0f, d1 = 0.0f, d2 = 0.0f, d3 = 0.0f;
        const float* wtcol = ws + WS_W2T + k;
        #pragma unroll 8
        for (int j = 0; j < HID; ++j) {
            float wt = wtcol[j*HID];
            float4 dz = dz2s[j*2 + ph];
            d0 = fmaf(dz.x, wt, d0);
            d1 = fmaf(dz.y, wt, d1);
            d2 = fmaf(dz.z, wt, d2);
            d3 = fmaf(dz.w, wt, d3);
        }
        float4 hh = shadeHT[k*2 + ph];
        float4 wl = l1ps[k];
        float dzl[4] = { (hh.x > 0.0f) ? d0 : 0.0f,
                         (hh.y > 0.0f) ? d1 : 0.0f,
                         (hh.z > 0.0f) ? d2 : 0.0f,
                         (hh.w > 0.0f) ? d3 : 0.0f };
        #pragma unroll
        for (int pp = 0; pp < 4; ++pp) {
            float g0 = wl.x*dzl[pp];
            float g1 = wl.y*dzl[pp];
            float g2 = wl.z*dzl[pp];
            #pragma unroll
            for (int off = 32; off > 0; off >>= 1) {
                g0 += __shfl_xor(g0, off, 64);
                g1 += __shfl_xor(g1, off, 64);
                g2 += __shfl_xor(g2, off, 64);
            }
            if (lane == 0) {
                redg[wv][0*4+pp] = g0;
                redg[wv][1*4+pp] = g1;
                redg[wv][2*4+pp] = g2;
            }
        }
    }
    __syncthreads();

    /* step 4: final per-pixel math */
    if (t < PIX) {
        int p = t, pp = p & 3;
        int wA = (p < 4) ? 0 : 2;
        float val  = redp[wA][pp*4+0] + redp[wA+1][pp*4+0] + b_sdf[0];
        float tex0 = redp[wA][pp*4+1] + redp[wA+1][pp*4+1] + b_tex[0];
        float tex1 = redp[wA][pp*4+2] + redp[wA+1][pp*4+2] + b_tex[1];
        float tex2 = redp[wA][pp*4+3] + redp[wA+1][pp*4+3] + b_tex[2];
        float g0 = redg[wA][0*4+pp] + redg[wA+1][0*4+pp];
        float g1 = redg[wA][1*4+pp] + redg[wA+1][1*4+pp];
        float g2 = redg[wA][2*4+pp] + redg[wA+1][2*4+pp];
        float nn = sqrtf(g0*g0 + g1*g1 + g2*g2) + 1e-8f;
        const float is3 = 0.57735026918962576f;
        float lam = (g0 + g1 + g2)*is3/nn;
        lam = fminf(fmaxf(lam, 0.0f), 1.0f);
        float hw = 1.0f/(1.0f + expf(val*SHARP));
        float sh = (0.2f + 0.8f*lam)*hw;
        int pg = tile*PIX + p;
        int x = pg & 63, y = pg >> 6;
        float o0 = 0.0f, o1 = 0.0f, o2 = 0.0f;
        if (maskq[p]) {
            o0 = sh/(1.0f + expf(-tex0));
            o1 = sh/(1.0f + expf(-tex1));
            o2 = sh/(1.0f + expf(-tex2));
        }
        out[((b*3 + 0)*IMG + y)*IMG + x] = o0;
        out[((b*3 + 1)*IMG + y)*IMG + x] = o1;
        out[((b*3 + 2)*IMG + y)*IMG + x] = o2;
    }
}

extern "C" void kernel_launch(void* const* d_in, const int* in_sizes, int n_in,
                              void* d_out, int out_size, void* d_ws, size_t ws_size,
                              hipStream_t stream) {
    const float* latents   = (const float*)d_in[0];
    const float* phis      = (const float*)d_in[1];
    const float* thetas    = (const float*)d_in[2];
    const float* samples_u = (const float*)d_in[3];
    const float* w1        = (const float*)d_in[4];
    const float* b1        = (const float*)d_in[5];
    const float* w2        = (const float*)d_in[6];
    const float* b2        = (const float*)d_in[7];
    const float* w_sdf     = (const float*)d_in[8];
    const float* b_sdf     = (const float*)d_in[9];
    const float* w_tex     = (const float*)d_in[10];
    const float* b_tex     = (const float*)d_in[11];
    float* out = (float*)d_out;
    float* ws  = (float*)d_ws;

    setup_all<<<dim3(76), dim3(256), 0, stream>>>(latents, phis, thetas, w1, b1, w2, ws);
    render_kernel<<<dim3(BATCH*(IMG*IMG/PIX)), dim3(256), 0, stream>>>(
        samples_u, w1, w2, b2, w_sdf, b_sdf, w_tex, b_tex, ws, out);
}